// Round 16
// baseline (135.273 us; speedup 1.0000x reference)
//
#include <hip/hip_runtime.h>
#include <hip/hip_bf16.h>

#define B_ 2
#define S_ 2048
#define D_ 1024
#define H_ 16

typedef __bf16 bf16x8 __attribute__((ext_vector_type(8)));
typedef __bf16 bf16x4v __attribute__((ext_vector_type(4)));
typedef float f32x4 __attribute__((ext_vector_type(4)));
typedef float f32x16 __attribute__((ext_vector_type(16)));

__device__ __forceinline__ float exp2fast(float x) {
  return __builtin_amdgcn_exp2f(x);  // v_exp_f32: D = 2^S0
}

__device__ __forceinline__ float max3f(float a, float b, float c) {
  return fmaxf(fmaxf(a, b), c);  // clang fuses to v_max3_f32
}

__device__ __forceinline__ unsigned short f2bf(float f) {
  unsigned int u = __float_as_uint(f);
  u += 0x7fff + ((u >> 16) & 1);   // RNE
  return (unsigned short)(u >> 16);
}

__device__ __forceinline__ unsigned int pk2(float x, float y) {
  unsigned int r;
  asm("v_cvt_pk_bf16_f32 %0, %1, %2" : "=v"(r) : "v"(x), "v"(y));
  return r;
}

__device__ __forceinline__ void gload_lds16(const void* g, void* l) {
  __builtin_amdgcn_global_load_lds(
      (const __attribute__((address_space(1))) void*)g,
      (__attribute__((address_space(3))) void*)l, 16, 0, 0);
}

// ---------------- prep: W fp32->bf16 cvt + mask all-ones check --------------
__global__ __launch_bounds__(256) void prep(
    const int* __restrict__ mask,
    const float* __restrict__ Wq, const float* __restrict__ Wk,
    const float* __restrict__ Wv, const float* __restrict__ Wo,
    unsigned short* __restrict__ Wqb, unsigned short* __restrict__ Wkb,
    unsigned short* __restrict__ Wvb, unsigned short* __restrict__ Wob,
    int* __restrict__ flag) {
  const int z = blockIdx.z;
  const int stride = gridDim.x * blockDim.x;
  const int tid0 = blockIdx.x * blockDim.x + threadIdx.x;
  if (z == 0) {
    const int n4 = D_ * D_ / 4;
#pragma unroll
    for (int t = 0; t < 4; t++) {
      const float* s = t == 0 ? Wq : (t == 1 ? Wk : (t == 2 ? Wv : Wo));
      unsigned short* d = t == 0 ? Wqb : (t == 1 ? Wkb : (t == 2 ? Wvb : Wob));
      for (int i = tid0; i < n4; i += stride) {
        float4 f = ((const float4*)s)[i];
        ushort4 o;
        o.x = f2bf(f.x); o.y = f2bf(f.y); o.z = f2bf(f.z); o.w = f2bf(f.w);
        ((ushort4*)d)[i] = o;
      }
    }
  } else {
    const int half = B_ * S_ * S_ / 8;
    const int base = (z - 1) * half;
    bool zf = false;
    for (int i = tid0; i < half; i += stride) {
      int4 mv = ((const int4*)mask)[base + i];
      zf |= (mv.x == 0) || (mv.y == 0) || (mv.z == 0) || (mv.w == 0);
    }
    if (__any(zf)) {
      if ((threadIdx.x & 63) == 0) atomicOr(flag, 1);
    }
  }
}

// -------- Q/K/V projections, m97 128x128 structure, FUSED fp32->bf16 A ------
// XCD-aware tile remap: hardware XCD = blockIdx.x (gridDim.x=8, round-robin),
// so each XCD owns 4 A row-panels x 8 col-blocks: A panel (512 KB fp32) loads
// into ONE XCD's L2 and is re-read 8x as L2 hits.
// T14 async-STAGE split: A(kt) held in registers from the previous iteration,
// ds_write at loop top; A(kt+1) float4 loads issued AFTER barrier1 so their
// drain (barrier2) is hidden under the MFMA phase.
__global__ __launch_bounds__(256, 2) void gemm_qkv(
    const float* __restrict__ qA, const float* __restrict__ kA,
    const float* __restrict__ vA,
    const unsigned short* __restrict__ Wq, const unsigned short* __restrict__ Wk,
    const unsigned short* __restrict__ Wv,
    unsigned short* __restrict__ Qp, unsigned short* __restrict__ Kp,
    unsigned short* __restrict__ Vtp) {
  __shared__ unsigned short As[128 * 64], Bs[128 * 64];
  const int z = blockIdx.z;
  const float* A = z == 0 ? qA : (z == 1 ? kA : vA);
  const unsigned short* W = z == 0 ? Wq : (z == 1 ? Wk : Wv);
  const int myY = blockIdx.x * 4 + (blockIdx.y >> 3);  // A row-panel
  const int myX = blockIdx.y & 7;                      // W col-panel
  const int rowBase = myY * 128, colBase = myX * 128;
  const int tid = threadIdx.x, lane = tid & 63, w = tid >> 6;
  const int wm = w >> 1, wn = w & 1, l15 = lane & 15, l4 = lane >> 4;
  f32x4 acc[4][4] = {};

  float4 areg[8];
  auto loadA = [&](int kt) {
#pragma unroll
    for (int i = 0; i < 8; i++) {
      int li = i * 256 + tid;          // 0..2047 (128 rows x 16 c4-chunks)
      int row = li >> 4, c4 = li & 15;
      areg[i] = *(const float4*)(A + (size_t)(rowBase + row) * 1024 +
                                 kt * 64 + c4 * 4);
    }
  };

  loadA(0);
  for (int kt = 0; kt < 16; ++kt) {
    // B staging via global_load_lds (pre-swizzled source, linear LDS)
#pragma unroll
    for (int i = 0; i < 4; i++) {
      int chunk = (w * 4 + i) * 64 + lane;
      int row = chunk >> 3, c = chunk & 7;
      int cs = c ^ (row & 7);
      gload_lds16(W + (size_t)(colBase + row) * 1024 + kt * 64 + cs * 8,
                  (char*)Bs + (w * 4 + i) * 1024);
    }
    // A(kt): cvt from registers, swizzled ds_write_b64
#pragma unroll
    for (int i = 0; i < 8; i++) {
      int li = i * 256 + tid;
      int row = li >> 4, c4 = li & 15;
      uint2 p;
      p.x = pk2(areg[i].x, areg[i].y);
      p.y = pk2(areg[i].z, areg[i].w);
      int slot = (c4 >> 1) ^ (row & 7);
      *(uint2*)((char*)As + row * 128 + slot * 16 + (c4 & 1) * 8) = p;
    }
    __syncthreads();
    if (kt + 1 < 16) loadA(kt + 1);  // prefetch; drained at barrier2 under MFMA
#pragma unroll
    for (int ks = 0; ks < 2; ks++) {
      bf16x8 af[4], bfr[4];
#pragma unroll
      for (int mi = 0; mi < 4; mi++) {
        int row = wm * 64 + mi * 16 + l15;
        af[mi] = *(const bf16x8*)((const char*)As + row * 128 +
                                  (((ks * 4 + l4) ^ (row & 7)) << 4));
      }
#pragma unroll
      for (int ni = 0; ni < 4; ni++) {
        int row = wn * 64 + ni * 16 + l15;
        bfr[ni] = *(const bf16x8*)((const char*)Bs + row * 128 +
                                   (((ks * 4 + l4) ^ (row & 7)) << 4));
      }
#pragma unroll
      for (int mi = 0; mi < 4; mi++)
#pragma unroll
        for (int ni = 0; ni < 4; ni++)
          acc[mi][ni] = __builtin_amdgcn_mfma_f32_16x16x32_bf16(
              af[mi], bfr[ni], acc[mi][ni], 0, 0, 0);
    }
    __syncthreads();
  }

  // epilogue
#pragma unroll
  for (int mi = 0; mi < 4; mi++)
#pragma unroll
    for (int ni = 0; ni < 4; ni++) {
      int gr0 = rowBase + wm * 64 + mi * 16 + l4 * 4;  // 4 consecutive s (r)
      int gc = colBase + wn * 64 + ni * 16 + l15;      // h*64 + d
      int b = gr0 >> 11, s0 = gr0 & 2047, h = gc >> 6, d = gc & 63;
      if (z == 2) {
        // packed: 4 consecutive s at fixed d -> one 8B store
        bf16x4v o;
#pragma unroll
        for (int r = 0; r < 4; r++) o[r] = (__bf16)acc[mi][ni][r];
        *(bf16x4v*)(Vtp + ((size_t)(b * 16 + h) * 64 + d) * 2048 + s0) = o;
      } else {
#pragma unroll
        for (int r = 0; r < 4; r++) {
          float v = acc[mi][ni][r];
          if (z == 0)
            Qp[(((size_t)(b * 16 + h) * 2048 + s0 + r) << 6) + d] =
                f2bf(v * 0.18033688011112042f);  // 0.125 * log2(e)
          else
            Kp[(((size_t)(b * 16 + h) * 2048 + s0 + r) << 6) + d] = f2bf(v);
        }
      }
    }
}

// Output projection, BM=128 x BN=64, XCD-remapped, bf16 Wo -------------------
__global__ __launch_bounds__(256, 2) void gemm_o(
    const unsigned short* __restrict__ A, const unsigned short* __restrict__ W,
    float* __restrict__ Out) {
  __shared__ unsigned short As[128 * 64], Bs[64 * 64];
  const int myY = (blockIdx.x & 7) * 4 + (blockIdx.y >> 3);   // [0,32)
  const int myX = (blockIdx.x >> 3) * 8 + (blockIdx.y & 7);   // [0,16)
  const int rowBase = myY * 128, colBase = myX * 64;
  const int tid = threadIdx.x, lane = tid & 63, w = tid >> 6;
  const int wm = w >> 1, wn = w & 1, l15 = lane & 15, l4 = lane >> 4;
  f32x4 acc[4][2] = {};
  for (int kt = 0; kt < 16; ++kt) {
#pragma unroll
    for (int i = 0; i < 4; i++) {
      int chunk = (w * 4 + i) * 64 + lane;
      int row = chunk >> 3, c = chunk & 7;
      int cs = c ^ (row & 7);
      gload_lds16(A + (size_t)(rowBase + row) * 1024 + kt * 64 + cs * 8,
                  (char*)As + (w * 4 + i) * 1024);
    }
#pragma unroll
    for (int i = 0; i < 2; i++) {
      int chunk = (w * 2 + i) * 64 + lane;
      int row = chunk >> 3, c = chunk & 7;
      int cs = c ^ (row & 7);
      gload_lds16(W + (size_t)(colBase + row) * 1024 + kt * 64 + cs * 8,
                  (char*)Bs + (w * 2 + i) * 1024);
    }
    __syncthreads();
#pragma unroll
    for (int ks = 0; ks < 2; ks++) {
      bf16x8 af[4], bfr[2];
#pragma unroll
      for (int mi = 0; mi < 4; mi++) {
        int row = wm * 64 + mi * 16 + l15;
        af[mi] = *(const bf16x8*)((const char*)As + row * 128 +
                                  (((ks * 4 + l4) ^ (row & 7)) << 4));
      }
#pragma unroll
      for (int ni = 0; ni < 2; ni++) {
        int row = wn * 32 + ni * 16 + l15;
        bfr[ni] = *(const bf16x8*)((const char*)Bs + row * 128 +
                                   (((ks * 4 + l4) ^ (row & 7)) << 4));
      }
#pragma unroll
      for (int mi = 0; mi < 4; mi++)
#pragma unroll
        for (int ni = 0; ni < 2; ni++)
          acc[mi][ni] = __builtin_amdgcn_mfma_f32_16x16x32_bf16(
              af[mi], bfr[ni], acc[mi][ni], 0, 0, 0);
    }
    __syncthreads();
  }
#pragma unroll
  for (int mi = 0; mi < 4; mi++)
#pragma unroll
    for (int ni = 0; ni < 2; ni++)
#pragma unroll
      for (int r = 0; r < 4; r++) {
        int gr = rowBase + wm * 64 + mi * 16 + l4 * 4 + r;
        int gc = colBase + wn * 32 + ni * 16 + l15;
        Out[(size_t)gr * 1024 + gc] = acc[mi][ni][r];
      }
}

// ---------------- flash attention: 32x32 MFMA, in-register P, MFMA l-sum ----
// (R8 version — best measured single-pass: 61.4 us)
__global__ __launch_bounds__(256, 2) void attn(
    const unsigned short* __restrict__ Qp, const unsigned short* __restrict__ Kp,
    const unsigned short* __restrict__ Vt, unsigned short* __restrict__ Xo,
    const int* __restrict__ flag, const int* __restrict__ mask) {
  __shared__ unsigned short Ks[2][64 * 64];  // [kpos][d], dbuf, swizzled
  __shared__ unsigned short Vs[2][64 * 64];  // [d][kpos], dbuf, swizzled
  const int tid = threadIdx.x, lane = tid & 63, w = tid >> 6;
  const int l31 = lane & 31, hi = lane >> 5;
  const int bid = ((blockIdx.x & 7) << 6) + (blockIdx.x >> 3);
  const int qblk = bid & 15;
  const int bh = bid >> 4;
  const int h = bh & 15, b = bh >> 4;
  const int q = qblk * 128 + w * 32 + l31;
  const int hz = *flag;

  const unsigned short* Kbase = Kp + (size_t)bh * S_ * 64;
  const unsigned short* Vbase = Vt + (size_t)bh * 64 * S_;

  bf16x8 qf[4];
#pragma unroll
  for (int ds = 0; ds < 4; ds++)
    qf[ds] = *(const bf16x8*)(Qp + ((size_t)bh * S_ + q) * 64 + ds * 16 + hi * 8);

  union { unsigned int u[4]; bf16x8 v; } ones;
  ones.u[0] = ones.u[1] = ones.u[2] = ones.u[3] = 0x3F803F80u;

  float m = -__builtin_inff();
  f32x16 lsum = {};
  f32x16 accO[2] = {};

  auto stage = [&](int kt, int buf) {
#pragma unroll
    for (int i = 0; i < 2; i++) {
      int ch = (w * 2 + i) * 64 + lane;
      int row = ch >> 3, c = ch & 7;
      int cs = c ^ (row & 7);
      gload_lds16(Kbase + (size_t)(kt * 64 + row) * 64 + cs * 8,
                  (char*)&Ks[buf][0] + (w * 2 + i) * 1024);
      gload_lds16(Vbase + (size_t)row * S_ + kt * 64 + cs * 8,
                  (char*)&Vs[buf][0] + (w * 2 + i) * 1024);
    }
  };

  auto body = [&](int kt, int cbuf) {
    f32x16 s[2] = {};
    __builtin_amdgcn_s_setprio(1);
#pragma unroll
    for (int ds = 0; ds < 4; ds++)
#pragma unroll
      for (int kb = 0; kb < 2; kb++) {
        int row = kb * 32 + l31;
        bf16x8 kf = *(const bf16x8*)((const char*)&Ks[cbuf][0] + row * 128 +
                                     (((ds * 2 + hi) ^ (row & 7)) << 4));
        s[kb] = __builtin_amdgcn_mfma_f32_32x32x16_bf16(kf, qf[ds], s[kb], 0, 0, 0);
      }
    __builtin_amdgcn_s_setprio(0);

    if (hz) {
#pragma unroll
      for (int kb = 0; kb < 2; kb++)
#pragma unroll
        for (int i = 0; i < 16; i++) {
          int kc = kt * 64 + kb * 32 + (i & 3) + 8 * (i >> 2) + 4 * hi;
          if (mask[((size_t)b * S_ + q) * S_ + kc] == 0) s[kb][i] = -1e9f;
        }
    }

    float a0 = max3f(s[0][0], s[0][1], s[0][2]);
    float a1 = max3f(s[0][3], s[0][4], s[0][5]);
    float a2 = max3f(s[0][6], s[0][7], s[0][8]);
    float a3 = max3f(s[0][9], s[0][10], s[0][11]);
    float a4 = max3f(s[0][12], s[0][13], s[0][14]);
    float a5 = max3f(s[0][15], s[1][0], s[1][1]);
    float a6 = max3f(s[1][2], s[1][3], s[1][4]);
    float a7 = max3f(s[1][5], s[1][6], s[1][7]);
    float a8 = max3f(s[1][8], s[1][9], s[1][10]);
    float a9 = max3f(s[1][11], s[1][12], s[1][13]);
    float aa = fmaxf(s[1][14], s[1][15]);
    float b0 = max3f(a0, a1, a2);
    float b1 = max3f(a3, a4, a5);
    float b2 = max3f(a6, a7, a8);
    float b3 = max3f(a9, aa, b0);
    float mx = max3f(b1, b2, b3);
    mx = fmaxf(mx, __shfl_xor(mx, 32));

    if (!__all(mx - m <= 8.f)) {
      float mn = fmaxf(m, mx);
      float al = exp2fast(m - mn);
      m = mn;
      lsum[0] *= al;
#pragma unroll
      for (int db = 0; db < 2; db++)
#pragma unroll
        for (int i = 0; i < 16; i++) accO[db][i] *= al;
    }

#pragma unroll
    for (int kb = 0; kb < 2; kb++)
#pragma unroll
      for (int i = 0; i < 16; i++) s[kb][i] = exp2fast(s[kb][i] - m);

#pragma unroll
    for (int ks2 = 0; ks2 < 4; ks2++) {
      union { unsigned int u[4]; bf16x8 v; } pb;
      {
        const int kb = ks2 >> 1;
        const int gb = (ks2 & 1) * 8;
        unsigned int a0u = pk2(s[kb][gb + 0], s[kb][gb + 1]);
        unsigned int a1u = pk2(s[kb][gb + 2], s[kb][gb + 3]);
        unsigned int b0u = pk2(s[kb][gb + 4], s[kb][gb + 5]);
        unsigned int b1u = pk2(s[kb][gb + 6], s[kb][gb + 7]);
        unsigned int t0 = hi ? a0u : b0u;
        unsigned int t1 = hi ? a1u : b1u;
        unsigned int r0 = __shfl_xor(t0, 32);
        unsigned int r1 = __shfl_xor(t1, 32);
        pb.u[0] = hi ? r0 : a0u;
        pb.u[1] = hi ? r1 : a1u;
        pb.u[2] = hi ? b0u : r0;
        pb.u[3] = hi ? b1u : r1;
      }
      __builtin_amdgcn_s_setprio(1);
      lsum = __builtin_amdgcn_mfma_f32_32x32x16_bf16(ones.v, pb.v, lsum, 0, 0, 0);
#pragma unroll
      for (int db = 0; db < 2; db++) {
        int row = db * 32 + l31;
        bf16x8 vf = *(const bf16x8*)((const char*)&Vs[cbuf][0] + row * 128 +
                                     (((ks2 * 2 + hi) ^ (row & 7)) << 4));
        accO[db] = __builtin_amdgcn_mfma_f32_32x32x16_bf16(vf, pb.v, accO[db], 0, 0, 0);
      }
      __builtin_amdgcn_s_setprio(0);
    }
  };

  stage(0, 0);
  for (int kt2 = 0; kt2 < 32; kt2 += 2) {
    __syncthreads();
    stage(kt2 + 1, 1);
    body(kt2, 0);
    __syncthreads();
    if (kt2 + 2 < 32) stage(kt2 + 2, 0);
    body(kt2 + 1, 1);
  }

  float rl = 1.0f / lsum[0];
  const size_t orow = (((size_t)(b * S_ + q)) << 10) + h * 64;
#pragma unroll
  for (int db = 0; db < 2; db++)
#pragma unroll
    for (int rq = 0; rq < 4; rq++) {
      bf16x4v o;
#pragma unroll
      for (int j = 0; j < 4; j++) o[j] = (__bf16)(accO[db][rq * 4 + j] * rl);
      *(bf16x4v*)(Xo + orow + db * 32 + rq * 8 + hi * 4) = o;
    }
}

extern "C" void kernel_launch(void* const* d_in, const int* in_sizes, int n_in,
                              void* d_out, int out_size, void* d_ws, size_t ws_size,
                              hipStream_t stream) {
  const float* q = (const float*)d_in[0];
  const float* k = (const float*)d_in[1];
  const float* v = (const float*)d_in[2];
  const int* mask = (const int*)d_in[3];
  const float* Wq = (const float*)d_in[4];
  const float* Wk = (const float*)d_in[5];
  const float* Wv = (const float*)d_in[6];
  const float* Wo = (const float*)d_in[7];

  char* ws = (char*)d_ws;
  const size_t MB = 1024 * 1024;
  unsigned short* Xo = (unsigned short*)(ws);              // 8 MB
  unsigned short* Wq16 = (unsigned short*)(ws + 24 * MB);  // 2 MB
  unsigned short* Wk16 = (unsigned short*)(ws + 26 * MB);
  unsigned short* Wv16 = (unsigned short*)(ws + 28 * MB);
  unsigned short* Wo16 = (unsigned short*)(ws + 30 * MB);
  unsigned short* Qp = (unsigned short*)(ws + 32 * MB);    // 8 MB [B,H,S,64]
  unsigned short* Kp = (unsigned short*)(ws + 40 * MB);    // 8 MB [B,H,S,64]
  unsigned short* Vtp = (unsigned short*)(ws + 48 * MB);   // 8 MB [B,H,64,S]
  int* flag = (int*)(ws + 56 * MB);

  (void)hipMemsetAsync(flag, 0, 4, stream);
  prep<<<dim3(1024, 1, 3), 256, 0, stream>>>(mask, Wq, Wk, Wv, Wo,
                                             Wq16, Wk16, Wv16, Wo16, flag);
  gemm_qkv<<<dim3(8, 32, 3), 256, 0, stream>>>(q, k, v, Wq16, Wk16, Wv16,
                                               Qp, Kp, Vtp);
  attn<<<dim3(512), 256, 0, stream>>>(Qp, Kp, Vtp, Xo, flag, mask);
  gemm_o<<<dim3(16, 32), 256, 0, stream>>>(Xo, Wo16, (float*)d_out);
}

// Round 17
// 127.317 us; speedup vs baseline: 1.0625x; 1.0625x over previous
//
#include <hip/hip_runtime.h>
#include <hip/hip_bf16.h>

#define B_ 2
#define S_ 2048
#define D_ 1024
#define H_ 16

typedef __bf16 bf16x8 __attribute__((ext_vector_type(8)));
typedef __bf16 bf16x4v __attribute__((ext_vector_type(4)));
typedef float f32x4 __attribute__((ext_vector_type(4)));
typedef float f32x16 __attribute__((ext_vector_type(16)));

__device__ __forceinline__ float exp2fast(float x) {
  return __builtin_amdgcn_exp2f(x);  // v_exp_f32: D = 2^S0
}

__device__ __forceinline__ float max3f(float a, float b, float c) {
  return fmaxf(fmaxf(a, b), c);  // clang fuses to v_max3_f32
}

__device__ __forceinline__ unsigned short f2bf(float f) {
  unsigned int u = __float_as_uint(f);
  u += 0x7fff + ((u >> 16) & 1);   // RNE
  return (unsigned short)(u >> 16);
}

__device__ __forceinline__ unsigned int pk2(float x, float y) {
  unsigned int r;
  asm("v_cvt_pk_bf16_f32 %0, %1, %2" : "=v"(r) : "v"(x), "v"(y));
  return r;
}

__device__ __forceinline__ void gload_lds16(const void* g, void* l) {
  __builtin_amdgcn_global_load_lds(
      (const __attribute__((address_space(1))) void*)g,
      (__attribute__((address_space(3))) void*)l, 16, 0, 0);
}

// ---------------- prep: W fp32->bf16 cvt + mask all-ones check --------------
__global__ __launch_bounds__(256) void prep(
    const int* __restrict__ mask,
    const float* __restrict__ Wq, const float* __restrict__ Wk,
    const float* __restrict__ Wv, const float* __restrict__ Wo,
    unsigned short* __restrict__ Wqb, unsigned short* __restrict__ Wkb,
    unsigned short* __restrict__ Wvb, unsigned short* __restrict__ Wob,
    int* __restrict__ flag) {
  const int z = blockIdx.z;
  const int stride = gridDim.x * blockDim.x;
  const int tid0 = blockIdx.x * blockDim.x + threadIdx.x;
  if (z == 0) {
    const int n4 = D_ * D_ / 4;
#pragma unroll
    for (int t = 0; t < 4; t++) {
      const float* s = t == 0 ? Wq : (t == 1 ? Wk : (t == 2 ? Wv : Wo));
      unsigned short* d = t == 0 ? Wqb : (t == 1 ? Wkb : (t == 2 ? Wvb : Wob));
      for (int i = tid0; i < n4; i += stride) {
        float4 f = ((const float4*)s)[i];
        ushort4 o;
        o.x = f2bf(f.x); o.y = f2bf(f.y); o.z = f2bf(f.z); o.w = f2bf(f.w);
        ((ushort4*)d)[i] = o;
      }
    }
  } else {
    const int half = B_ * S_ * S_ / 8;
    const int base = (z - 1) * half;
    bool zf = false;
    for (int i = tid0; i < half; i += stride) {
      int4 mv = ((const int4*)mask)[base + i];
      zf |= (mv.x == 0) || (mv.y == 0) || (mv.z == 0) || (mv.w == 0);
    }
    if (__any(zf)) {
      if ((threadIdx.x & 63) == 0) atomicOr(flag, 1);
    }
  }
}

// -------- Q/K/V projections, m97 128x128 structure, FUSED fp32->bf16 A ------
// XCD-aware tile remap: hardware XCD = blockIdx.x (gridDim.x=8, round-robin),
// so each XCD owns 4 A row-panels x 8 col-blocks: A panel (512 KB fp32) loads
// into ONE XCD's L2 and is re-read 8x as L2 hits.
__global__ __launch_bounds__(256, 2) void gemm_qkv(
    const float* __restrict__ qA, const float* __restrict__ kA,
    const float* __restrict__ vA,
    const unsigned short* __restrict__ Wq, const unsigned short* __restrict__ Wk,
    const unsigned short* __restrict__ Wv,
    unsigned short* __restrict__ Qp, unsigned short* __restrict__ Kp,
    unsigned short* __restrict__ Vtp) {
  __shared__ unsigned short As[128 * 64], Bs[128 * 64];
  const int z = blockIdx.z;
  const float* A = z == 0 ? qA : (z == 1 ? kA : vA);
  const unsigned short* W = z == 0 ? Wq : (z == 1 ? Wk : Wv);
  const int myY = blockIdx.x * 4 + (blockIdx.y >> 3);  // A row-panel
  const int myX = blockIdx.y & 7;                      // W col-panel
  const int rowBase = myY * 128, colBase = myX * 128;
  const int tid = threadIdx.x, lane = tid & 63, w = tid >> 6;
  const int wm = w >> 1, wn = w & 1, l15 = lane & 15, l4 = lane >> 4;
  f32x4 acc[4][4] = {};

  for (int kt = 0; kt < 16; ++kt) {
    // B staging via global_load_lds (pre-swizzled source, linear LDS)
#pragma unroll
    for (int i = 0; i < 4; i++) {
      int chunk = (w * 4 + i) * 64 + lane;
      int row = chunk >> 3, c = chunk & 7;
      int cs = c ^ (row & 7);
      gload_lds16(W + (size_t)(colBase + row) * 1024 + kt * 64 + cs * 8,
                  (char*)Bs + (w * 4 + i) * 1024);
    }
    // A staging: fp32 -> bf16 in-register, swizzled ds_write_b64
#pragma unroll
    for (int i = 0; i < 8; i++) {
      int li = i * 256 + tid;          // 0..2047 (128 rows x 16 c4-chunks)
      int row = li >> 4, c4 = li & 15; // c4: 4 fp32 = 4 bf16 = 8B out
      float4 f = *(const float4*)(A + (size_t)(rowBase + row) * 1024 +
                                  kt * 64 + c4 * 4);
      uint2 p;
      p.x = pk2(f.x, f.y);
      p.y = pk2(f.z, f.w);
      int slot = (c4 >> 1) ^ (row & 7);
      *(uint2*)((char*)As + row * 128 + slot * 16 + (c4 & 1) * 8) = p;
    }
    __syncthreads();
#pragma unroll
    for (int ks = 0; ks < 2; ks++) {
      bf16x8 af[4], bfr[4];
#pragma unroll
      for (int mi = 0; mi < 4; mi++) {
        int row = wm * 64 + mi * 16 + l15;
        af[mi] = *(const bf16x8*)((const char*)As + row * 128 +
                                  (((ks * 4 + l4) ^ (row & 7)) << 4));
      }
#pragma unroll
      for (int ni = 0; ni < 4; ni++) {
        int row = wn * 64 + ni * 16 + l15;
        bfr[ni] = *(const bf16x8*)((const char*)Bs + row * 128 +
                                   (((ks * 4 + l4) ^ (row & 7)) << 4));
      }
#pragma unroll
      for (int mi = 0; mi < 4; mi++)
#pragma unroll
        for (int ni = 0; ni < 4; ni++)
          acc[mi][ni] = __builtin_amdgcn_mfma_f32_16x16x32_bf16(
              af[mi], bfr[ni], acc[mi][ni], 0, 0, 0);
    }
    __syncthreads();
  }

  // epilogue
#pragma unroll
  for (int mi = 0; mi < 4; mi++)
#pragma unroll
    for (int ni = 0; ni < 4; ni++) {
      int gr0 = rowBase + wm * 64 + mi * 16 + l4 * 4;  // 4 consecutive s (r)
      int gc = colBase + wn * 64 + ni * 16 + l15;      // h*64 + d
      int b = gr0 >> 11, s0 = gr0 & 2047, h = gc >> 6, d = gc & 63;
      if (z == 2) {
        // packed: 4 consecutive s at fixed d -> one 8B store
        bf16x4v o;
#pragma unroll
        for (int r = 0; r < 4; r++) o[r] = (__bf16)acc[mi][ni][r];
        *(bf16x4v*)(Vtp + ((size_t)(b * 16 + h) * 64 + d) * 2048 + s0) = o;
      } else {
#pragma unroll
        for (int r = 0; r < 4; r++) {
          float v = acc[mi][ni][r];
          if (z == 0)
            Qp[(((size_t)(b * 16 + h) * 2048 + s0 + r) << 6) + d] =
                f2bf(v * 0.18033688011112042f);  // 0.125 * log2(e)
          else
            Kp[(((size_t)(b * 16 + h) * 2048 + s0 + r) << 6) + d] = f2bf(v);
        }
      }
    }
}

// Output projection, BM=128 x BN=64, XCD-remapped, bf16 Wo -------------------
__global__ __launch_bounds__(256, 2) void gemm_o(
    const unsigned short* __restrict__ A, const unsigned short* __restrict__ W,
    float* __restrict__ Out) {
  __shared__ unsigned short As[128 * 64], Bs[64 * 64];
  const int myY = (blockIdx.x & 7) * 4 + (blockIdx.y >> 3);   // [0,32)
  const int myX = (blockIdx.x >> 3) * 8 + (blockIdx.y & 7);   // [0,16)
  const int rowBase = myY * 128, colBase = myX * 64;
  const int tid = threadIdx.x, lane = tid & 63, w = tid >> 6;
  const int wm = w >> 1, wn = w & 1, l15 = lane & 15, l4 = lane >> 4;
  f32x4 acc[4][2] = {};
  for (int kt = 0; kt < 16; ++kt) {
#pragma unroll
    for (int i = 0; i < 4; i++) {
      int chunk = (w * 4 + i) * 64 + lane;
      int row = chunk >> 3, c = chunk & 7;
      int cs = c ^ (row & 7);
      gload_lds16(A + (size_t)(rowBase + row) * 1024 + kt * 64 + cs * 8,
                  (char*)As + (w * 4 + i) * 1024);
    }
#pragma unroll
    for (int i = 0; i < 2; i++) {
      int chunk = (w * 2 + i) * 64 + lane;
      int row = chunk >> 3, c = chunk & 7;
      int cs = c ^ (row & 7);
      gload_lds16(W + (size_t)(colBase + row) * 1024 + kt * 64 + cs * 8,
                  (char*)Bs + (w * 2 + i) * 1024);
    }
    __syncthreads();
#pragma unroll
    for (int ks = 0; ks < 2; ks++) {
      bf16x8 af[4], bfr[2];
#pragma unroll
      for (int mi = 0; mi < 4; mi++) {
        int row = wm * 64 + mi * 16 + l15;
        af[mi] = *(const bf16x8*)((const char*)As + row * 128 +
                                  (((ks * 4 + l4) ^ (row & 7)) << 4));
      }
#pragma unroll
      for (int ni = 0; ni < 2; ni++) {
        int row = wn * 32 + ni * 16 + l15;
        bfr[ni] = *(const bf16x8*)((const char*)Bs + row * 128 +
                                   (((ks * 4 + l4) ^ (row & 7)) << 4));
      }
#pragma unroll
      for (int mi = 0; mi < 4; mi++)
#pragma unroll
        for (int ni = 0; ni < 2; ni++)
          acc[mi][ni] = __builtin_amdgcn_mfma_f32_16x16x32_bf16(
              af[mi], bfr[ni], acc[mi][ni], 0, 0, 0);
    }
    __syncthreads();
  }
#pragma unroll
  for (int mi = 0; mi < 4; mi++)
#pragma unroll
    for (int ni = 0; ni < 2; ni++)
#pragma unroll
      for (int r = 0; r < 4; r++) {
        int gr = rowBase + wm * 64 + mi * 16 + l4 * 4 + r;
        int gc = colBase + wn * 32 + ni * 16 + l15;
        Out[(size_t)gr * 1024 + gc] = acc[mi][ni][r];
      }
}

// ---------------- flash attention: 32x32 MFMA, in-register P, MFMA l-sum ----
// (R8 version — best measured single-pass: 61.4 us)
__global__ __launch_bounds__(256, 2) void attn(
    const unsigned short* __restrict__ Qp, const unsigned short* __restrict__ Kp,
    const unsigned short* __restrict__ Vt, unsigned short* __restrict__ Xo,
    const int* __restrict__ flag, const int* __restrict__ mask) {
  __shared__ unsigned short Ks[2][64 * 64];  // [kpos][d], dbuf, swizzled
  __shared__ unsigned short Vs[2][64 * 64];  // [d][kpos], dbuf, swizzled
  const int tid = threadIdx.x, lane = tid & 63, w = tid >> 6;
  const int l31 = lane & 31, hi = lane >> 5;
  const int bid = ((blockIdx.x & 7) << 6) + (blockIdx.x >> 3);
  const int qblk = bid & 15;
  const int bh = bid >> 4;
  const int h = bh & 15, b = bh >> 4;
  const int q = qblk * 128 + w * 32 + l31;
  const int hz = *flag;

  const unsigned short* Kbase = Kp + (size_t)bh * S_ * 64;
  const unsigned short* Vbase = Vt + (size_t)bh * 64 * S_;

  bf16x8 qf[4];
#pragma unroll
  for (int ds = 0; ds < 4; ds++)
    qf[ds] = *(const bf16x8*)(Qp + ((size_t)bh * S_ + q) * 64 + ds * 16 + hi * 8);

  union { unsigned int u[4]; bf16x8 v; } ones;
  ones.u[0] = ones.u[1] = ones.u[2] = ones.u[3] = 0x3F803F80u;

  float m = -__builtin_inff();
  f32x16 lsum = {};
  f32x16 accO[2] = {};

  auto stage = [&](int kt, int buf) {
#pragma unroll
    for (int i = 0; i < 2; i++) {
      int ch = (w * 2 + i) * 64 + lane;
      int row = ch >> 3, c = ch & 7;
      int cs = c ^ (row & 7);
      gload_lds16(Kbase + (size_t)(kt * 64 + row) * 64 + cs * 8,
                  (char*)&Ks[buf][0] + (w * 2 + i) * 1024);
      gload_lds16(Vbase + (size_t)row * S_ + kt * 64 + cs * 8,
                  (char*)&Vs[buf][0] + (w * 2 + i) * 1024);
    }
  };

  auto body = [&](int kt, int cbuf) {
    f32x16 s[2] = {};
    __builtin_amdgcn_s_setprio(1);
#pragma unroll
    for (int ds = 0; ds < 4; ds++)
#pragma unroll
      for (int kb = 0; kb < 2; kb++) {
        int row = kb * 32 + l31;
        bf16x8 kf = *(const bf16x8*)((const char*)&Ks[cbuf][0] + row * 128 +
                                     (((ds * 2 + hi) ^ (row & 7)) << 4));
        s[kb] = __builtin_amdgcn_mfma_f32_32x32x16_bf16(kf, qf[ds], s[kb], 0, 0, 0);
      }
    __builtin_amdgcn_s_setprio(0);

    if (hz) {
#pragma unroll
      for (int kb = 0; kb < 2; kb++)
#pragma unroll
        for (int i = 0; i < 16; i++) {
          int kc = kt * 64 + kb * 32 + (i & 3) + 8 * (i >> 2) + 4 * hi;
          if (mask[((size_t)b * S_ + q) * S_ + kc] == 0) s[kb][i] = -1e9f;
        }
    }

    float a0 = max3f(s[0][0], s[0][1], s[0][2]);
    float a1 = max3f(s[0][3], s[0][4], s[0][5]);
    float a2 = max3f(s[0][6], s[0][7], s[0][8]);
    float a3 = max3f(s[0][9], s[0][10], s[0][11]);
    float a4 = max3f(s[0][12], s[0][13], s[0][14]);
    float a5 = max3f(s[0][15], s[1][0], s[1][1]);
    float a6 = max3f(s[1][2], s[1][3], s[1][4]);
    float a7 = max3f(s[1][5], s[1][6], s[1][7]);
    float a8 = max3f(s[1][8], s[1][9], s[1][10]);
    float a9 = max3f(s[1][11], s[1][12], s[1][13]);
    float aa = fmaxf(s[1][14], s[1][15]);
    float b0 = max3f(a0, a1, a2);
    float b1 = max3f(a3, a4, a5);
    float b2 = max3f(a6, a7, a8);
    float b3 = max3f(a9, aa, b0);
    float mx = max3f(b1, b2, b3);
    mx = fmaxf(mx, __shfl_xor(mx, 32));

    if (!__all(mx - m <= 8.f)) {
      float mn = fmaxf(m, mx);
      float al = exp2fast(m - mn);
      m = mn;
      lsum[0] *= al;
#pragma unroll
      for (int db = 0; db < 2; db++)
#pragma unroll
        for (int i = 0; i < 16; i++) accO[db][i] *= al;
    }

#pragma unroll
    for (int kb = 0; kb < 2; kb++)
#pragma unroll
      for (int i = 0; i < 16; i++) s[kb][i] = exp2fast(s[kb][i] - m);

#pragma unroll
    for (int ks2 = 0; ks2 < 4; ks2++) {
      union { unsigned int u[4]; bf16x8 v; } pb;
      {
        const int kb = ks2 >> 1;
        const int gb = (ks2 & 1) * 8;
        unsigned int a0u = pk2(s[kb][gb + 0], s[kb][gb + 1]);
        unsigned int a1u = pk2(s[kb][gb + 2], s[kb][gb + 3]);
        unsigned int b0u = pk2(s[kb][gb + 4], s[kb][gb + 5]);
        unsigned int b1u = pk2(s[kb][gb + 6], s[kb][gb + 7]);
        unsigned int t0 = hi ? a0u : b0u;
        unsigned int t1 = hi ? a1u : b1u;
        unsigned int r0 = __shfl_xor(t0, 32);
        unsigned int r1 = __shfl_xor(t1, 32);
        pb.u[0] = hi ? r0 : a0u;
        pb.u[1] = hi ? r1 : a1u;
        pb.u[2] = hi ? b0u : r0;
        pb.u[3] = hi ? b1u : r1;
      }
      __builtin_amdgcn_s_setprio(1);
      lsum = __builtin_amdgcn_mfma_f32_32x32x16_bf16(ones.v, pb.v, lsum, 0, 0, 0);
#pragma unroll
      for (int db = 0; db < 2; db++) {
        int row = db * 32 + l31;
        bf16x8 vf = *(const bf16x8*)((const char*)&Vs[cbuf][0] + row * 128 +
                                     (((ks2 * 2 + hi) ^ (row & 7)) << 4));
        accO[db] = __builtin_amdgcn_mfma_f32_32x32x16_bf16(vf, pb.v, accO[db], 0, 0, 0);
      }
      __builtin_amdgcn_s_setprio(0);
    }
  };

  stage(0, 0);
  for (int kt2 = 0; kt2 < 32; kt2 += 2) {
    __syncthreads();
    stage(kt2 + 1, 1);
    body(kt2, 0);
    __syncthreads();
    if (kt2 + 2 < 32) stage(kt2 + 2, 0);
    body(kt2 + 1, 1);
  }

  float rl = 1.0f / lsum[0];
  const size_t orow = (((size_t)(b * S_ + q)) << 10) + h * 64;
#pragma unroll
  for (int db = 0; db < 2; db++)
#pragma unroll
    for (int rq = 0; rq < 4; rq++) {
      bf16x4v o;
#pragma unroll
      for (int j = 0; j < 4; j++) o[j] = (__bf16)(accO[db][rq * 4 + j] * rl);
      *(bf16x4v*)(Xo + orow + db * 32 + rq * 8 + hi * 4) = o;
    }
}

extern "C" void kernel_launch(void* const* d_in, const int* in_sizes, int n_in,
                              void* d_out, int out_size, void* d_ws, size_t ws_size,
                              hipStream_t stream) {
  const float* q = (const float*)d_in[0];
  const float* k = (const float*)d_in[1];
  const float* v = (const float*)d_in[2];
  const int* mask = (const int*)d_in[3];
  const float* Wq = (const float*)d_in[4];
  const float* Wk = (const float*)d_in[5];
  const float* Wv = (const float*)d_in[6];
  const float* Wo = (const float*)d_in[7];

  char* ws = (char*)d_ws;
  const size_t MB = 1024 * 1024;
  unsigned short* Xo = (unsigned short*)(ws);              // 8 MB
  unsigned short* Wq16 = (unsigned short*)(ws + 24 * MB);  // 2 MB
  unsigned short* Wk16 = (unsigned short*)(ws + 26 * MB);
  unsigned short* Wv16 = (unsigned short*)(ws + 28 * MB);
  unsigned short* Wo16 = (unsigned short*)(ws + 30 * MB);
  unsigned short* Qp = (unsigned short*)(ws + 32 * MB);    // 8 MB [B,H,S,64]
  unsigned short* Kp = (unsigned short*)(ws + 40 * MB);    // 8 MB [B,H,S,64]
  unsigned short* Vtp = (unsigned short*)(ws + 48 * MB);   // 8 MB [B,H,64,S]
  int* flag = (int*)(ws + 56 * MB);

  (void)hipMemsetAsync(flag, 0, 4, stream);
  prep<<<dim3(1024, 1, 3), 256, 0, stream>>>(mask, Wq, Wk, Wv, Wo,
                                             Wq16, Wk16, Wv16, Wo16, flag);
  gemm_qkv<<<dim3(8, 32, 3), 256, 0, stream>>>(q, k, v, Wq16, Wk16, Wv16,
                                               Qp, Kp, Vtp);
  attn<<<dim3(512), 256, 0, stream>>>(Qp, Kp, Vtp, Xo, flag, mask);
  gemm_o<<<dim3(16, 32), 256, 0, stream>>>(Xo, Wo16, (float*)d_out);
}

// Round 19
// 127.278 us; speedup vs baseline: 1.0628x; 1.0003x over previous
//
#include <hip/hip_runtime.h>
#include <hip/hip_bf16.h>

#define B_ 2
#define S_ 2048
#define D_ 1024
#define H_ 16

typedef __bf16 bf16x8 __attribute__((ext_vector_type(8)));
typedef __bf16 bf16x4v __attribute__((ext_vector_type(4)));
typedef float f32x4 __attribute__((ext_vector_type(4)));
typedef float f32x16 __attribute__((ext_vector_type(16)));

__device__ __forceinline__ float exp2fast(float x) {
  return __builtin_amdgcn_exp2f(x);  // v_exp_f32: D = 2^S0
}

__device__ __forceinline__ float max3f(float a, float b, float c) {
  return fmaxf(fmaxf(a, b), c);  // clang fuses to v_max3_f32
}

__device__ __forceinline__ unsigned short f2bf(float f) {
  unsigned int u = __float_as_uint(f);
  u += 0x7fff + ((u >> 16) & 1);   // RNE
  return (unsigned short)(u >> 16);
}

__device__ __forceinline__ unsigned int pk2(float x, float y) {
  unsigned int r;
  asm("v_cvt_pk_bf16_f32 %0, %1, %2" : "=v"(r) : "v"(x), "v"(y));
  return r;
}

__device__ __forceinline__ void gload_lds16(const void* g, void* l) {
  __builtin_amdgcn_global_load_lds(
      (const __attribute__((address_space(1))) void*)g,
      (__attribute__((address_space(3))) void*)l, 16, 0, 0);
}

// ---------------- prep: W fp32->bf16 cvt + mask all-ones check --------------
__global__ __launch_bounds__(256) void prep(
    const int* __restrict__ mask,
    const float* __restrict__ Wq, const float* __restrict__ Wk,
    const float* __restrict__ Wv, const float* __restrict__ Wo,
    unsigned short* __restrict__ Wqb, unsigned short* __restrict__ Wkb,
    unsigned short* __restrict__ Wvb, unsigned short* __restrict__ Wob,
    int* __restrict__ flag) {
  const int z = blockIdx.z;
  const int stride = gridDim.x * blockDim.x;
  const int tid0 = blockIdx.x * blockDim.x + threadIdx.x;
  if (z == 0) {
    const int n4 = D_ * D_ / 4;
#pragma unroll
    for (int t = 0; t < 4; t++) {
      const float* s = t == 0 ? Wq : (t == 1 ? Wk : (t == 2 ? Wv : Wo));
      unsigned short* d = t == 0 ? Wqb : (t == 1 ? Wkb : (t == 2 ? Wvb : Wob));
      for (int i = tid0; i < n4; i += stride) {
        float4 f = ((const float4*)s)[i];
        ushort4 o;
        o.x = f2bf(f.x); o.y = f2bf(f.y); o.z = f2bf(f.z); o.w = f2bf(f.w);
        ((ushort4*)d)[i] = o;
      }
    }
  } else {
    const int half = B_ * S_ * S_ / 8;
    const int base = (z - 1) * half;
    bool zf = false;
    for (int i = tid0; i < half; i += stride) {
      int4 mv = ((const int4*)mask)[base + i];
      zf |= (mv.x == 0) || (mv.y == 0) || (mv.z == 0) || (mv.w == 0);
    }
    if (__any(zf)) {
      if ((threadIdx.x & 63) == 0) atomicOr(flag, 1);
    }
  }
}

// -------- Q/K/V projections, m97 128x128 structure, FUSED fp32->bf16 A ------
// XCD-aware tile remap: hardware XCD = blockIdx.x (gridDim.x=8, round-robin),
// so each XCD owns 4 A row-panels x 8 col-blocks: A panel (512 KB fp32) loads
// into ONE XCD's L2 and is re-read 8x as L2 hits.
__global__ __launch_bounds__(256, 2) void gemm_qkv(
    const float* __restrict__ qA, const float* __restrict__ kA,
    const float* __restrict__ vA,
    const unsigned short* __restrict__ Wq, const unsigned short* __restrict__ Wk,
    const unsigned short* __restrict__ Wv,
    unsigned short* __restrict__ Qp, unsigned short* __restrict__ Kp,
    unsigned short* __restrict__ Vtp) {
  __shared__ unsigned short As[128 * 64], Bs[128 * 64];
  const int z = blockIdx.z;
  const float* A = z == 0 ? qA : (z == 1 ? kA : vA);
  const unsigned short* W = z == 0 ? Wq : (z == 1 ? Wk : Wv);
  const int myY = blockIdx.x * 4 + (blockIdx.y >> 3);  // A row-panel
  const int myX = blockIdx.y & 7;                      // W col-panel
  const int rowBase = myY * 128, colBase = myX * 128;
  const int tid = threadIdx.x, lane = tid & 63, w = tid >> 6;
  const int wm = w >> 1, wn = w & 1, l15 = lane & 15, l4 = lane >> 4;
  f32x4 acc[4][4] = {};

  for (int kt = 0; kt < 16; ++kt) {
    // B staging via global_load_lds (pre-swizzled source, linear LDS)
#pragma unroll
    for (int i = 0; i < 4; i++) {
      int chunk = (w * 4 + i) * 64 + lane;
      int row = chunk >> 3, c = chunk & 7;
      int cs = c ^ (row & 7);
      gload_lds16(W + (size_t)(colBase + row) * 1024 + kt * 64 + cs * 8,
                  (char*)Bs + (w * 4 + i) * 1024);
    }
    // A staging: fp32 -> bf16 in-register, swizzled ds_write_b64
#pragma unroll
    for (int i = 0; i < 8; i++) {
      int li = i * 256 + tid;          // 0..2047 (128 rows x 16 c4-chunks)
      int row = li >> 4, c4 = li & 15; // c4: 4 fp32 = 4 bf16 = 8B out
      float4 f = *(const float4*)(A + (size_t)(rowBase + row) * 1024 +
                                  kt * 64 + c4 * 4);
      uint2 p;
      p.x = pk2(f.x, f.y);
      p.y = pk2(f.z, f.w);
      int slot = (c4 >> 1) ^ (row & 7);
      *(uint2*)((char*)As + row * 128 + slot * 16 + (c4 & 1) * 8) = p;
    }
    __syncthreads();
#pragma unroll
    for (int ks = 0; ks < 2; ks++) {
      bf16x8 af[4], bfr[4];
#pragma unroll
      for (int mi = 0; mi < 4; mi++) {
        int row = wm * 64 + mi * 16 + l15;
        af[mi] = *(const bf16x8*)((const char*)As + row * 128 +
                                  (((ks * 4 + l4) ^ (row & 7)) << 4));
      }
#pragma unroll
      for (int ni = 0; ni < 4; ni++) {
        int row = wn * 64 + ni * 16 + l15;
        bfr[ni] = *(const bf16x8*)((const char*)Bs + row * 128 +
                                   (((ks * 4 + l4) ^ (row & 7)) << 4));
      }
#pragma unroll
      for (int mi = 0; mi < 4; mi++)
#pragma unroll
        for (int ni = 0; ni < 4; ni++)
          acc[mi][ni] = __builtin_amdgcn_mfma_f32_16x16x32_bf16(
              af[mi], bfr[ni], acc[mi][ni], 0, 0, 0);
    }
    __syncthreads();
  }

  // epilogue
#pragma unroll
  for (int mi = 0; mi < 4; mi++)
#pragma unroll
    for (int ni = 0; ni < 4; ni++) {
      int gr0 = rowBase + wm * 64 + mi * 16 + l4 * 4;  // 4 consecutive s (r)
      int gc = colBase + wn * 64 + ni * 16 + l15;      // h*64 + d
      int b = gr0 >> 11, s0 = gr0 & 2047, h = gc >> 6, d = gc & 63;
      if (z == 2) {
        // packed: 4 consecutive s at fixed d -> one 8B store
        bf16x4v o;
#pragma unroll
        for (int r = 0; r < 4; r++) o[r] = (__bf16)acc[mi][ni][r];
        *(bf16x4v*)(Vtp + ((size_t)(b * 16 + h) * 64 + d) * 2048 + s0) = o;
      } else {
#pragma unroll
        for (int r = 0; r < 4; r++) {
          float v = acc[mi][ni][r];
          if (z == 0)
            Qp[(((size_t)(b * 16 + h) * 2048 + s0 + r) << 6) + d] =
                f2bf(v * 0.18033688011112042f);  // 0.125 * log2(e)
          else
            Kp[(((size_t)(b * 16 + h) * 2048 + s0 + r) << 6) + d] = f2bf(v);
        }
      }
    }
}

// Output projection, BM=128 x BN=64, XCD-remapped, bf16 Wo -------------------
__global__ __launch_bounds__(256, 2) void gemm_o(
    const unsigned short* __restrict__ A, const unsigned short* __restrict__ W,
    float* __restrict__ Out) {
  __shared__ unsigned short As[128 * 64], Bs[64 * 64];
  const int myY = (blockIdx.x & 7) * 4 + (blockIdx.y >> 3);   // [0,32)
  const int myX = (blockIdx.x >> 3) * 8 + (blockIdx.y & 7);   // [0,16)
  const int rowBase = myY * 128, colBase = myX * 64;
  const int tid = threadIdx.x, lane = tid & 63, w = tid >> 6;
  const int wm = w >> 1, wn = w & 1, l15 = lane & 15, l4 = lane >> 4;
  f32x4 acc[4][2] = {};
  for (int kt = 0; kt < 16; ++kt) {
#pragma unroll
    for (int i = 0; i < 4; i++) {
      int chunk = (w * 4 + i) * 64 + lane;
      int row = chunk >> 3, c = chunk & 7;
      int cs = c ^ (row & 7);
      gload_lds16(A + (size_t)(rowBase + row) * 1024 + kt * 64 + cs * 8,
                  (char*)As + (w * 4 + i) * 1024);
    }
#pragma unroll
    for (int i = 0; i < 2; i++) {
      int chunk = (w * 2 + i) * 64 + lane;
      int row = chunk >> 3, c = chunk & 7;
      int cs = c ^ (row & 7);
      gload_lds16(W + (size_t)(colBase + row) * 1024 + kt * 64 + cs * 8,
                  (char*)Bs + (w * 2 + i) * 1024);
    }
    __syncthreads();
#pragma unroll
    for (int ks = 0; ks < 2; ks++) {
      bf16x8 af[4], bfr[2];
#pragma unroll
      for (int mi = 0; mi < 4; mi++) {
        int row = wm * 64 + mi * 16 + l15;
        af[mi] = *(const bf16x8*)((const char*)As + row * 128 +
                                  (((ks * 4 + l4) ^ (row & 7)) << 4));
      }
#pragma unroll
      for (int ni = 0; ni < 2; ni++) {
        int row = wn * 32 + ni * 16 + l15;
        bfr[ni] = *(const bf16x8*)((const char*)Bs + row * 128 +
                                   (((ks * 4 + l4) ^ (row & 7)) << 4));
      }
#pragma unroll
      for (int mi = 0; mi < 4; mi++)
#pragma unroll
        for (int ni = 0; ni < 2; ni++)
          acc[mi][ni] = __builtin_amdgcn_mfma_f32_16x16x32_bf16(
              af[mi], bfr[ni], acc[mi][ni], 0, 0, 0);
    }
    __syncthreads();
  }
#pragma unroll
  for (int mi = 0; mi < 4; mi++)
#pragma unroll
    for (int ni = 0; ni < 2; ni++)
#pragma unroll
      for (int r = 0; r < 4; r++) {
        int gr = rowBase + wm * 64 + mi * 16 + l4 * 4 + r;
        int gc = colBase + wn * 32 + ni * 16 + l15;
        Out[(size_t)gr * 1024 + gc] = acc[mi][ni][r];
      }
}

// ---------------- flash attention: 32x32 MFMA, in-register P, MFMA l-sum ----
// (R8 version — best measured single-pass: 61.4 us)
__global__ __launch_bounds__(256, 2) void attn(
    const unsigned short* __restrict__ Qp, const unsigned short* __restrict__ Kp,
    const unsigned short* __restrict__ Vt, unsigned short* __restrict__ Xo,
    const int* __restrict__ flag, const int* __restrict__ mask) {
  __shared__ unsigned short Ks[2][64 * 64];  // [kpos][d], dbuf, swizzled
  __shared__ unsigned short Vs[2][64 * 64];  // [d][kpos], dbuf, swizzled
  const int tid = threadIdx.x, lane = tid & 63, w = tid >> 6;
  const int l31 = lane & 31, hi = lane >> 5;
  const int bid = ((blockIdx.x & 7) << 6) + (blockIdx.x >> 3);
  const int qblk = bid & 15;
  const int bh = bid >> 4;
  const int h = bh & 15, b = bh >> 4;
  const int q = qblk * 128 + w * 32 + l31;
  const int hz = *flag;

  const unsigned short* Kbase = Kp + (size_t)bh * S_ * 64;
  const unsigned short* Vbase = Vt + (size_t)bh * 64 * S_;

  bf16x8 qf[4];
#pragma unroll
  for (int ds = 0; ds < 4; ds++)
    qf[ds] = *(const bf16x8*)(Qp + ((size_t)bh * S_ + q) * 64 + ds * 16 + hi * 8);

  union { unsigned int u[4]; bf16x8 v; } ones;
  ones.u[0] = ones.u[1] = ones.u[2] = ones.u[3] = 0x3F803F80u;

  float m = -__builtin_inff();
  f32x16 lsum = {};
  f32x16 accO[2] = {};

  auto stage = [&](int kt, int buf) {
#pragma unroll
    for (int i = 0; i < 2; i++) {
      int ch = (w * 2 + i) * 64 + lane;
      int row = ch >> 3, c = ch & 7;
      int cs = c ^ (row & 7);
      gload_lds16(Kbase + (size_t)(kt * 64 + row) * 64 + cs * 8,
                  (char*)&Ks[buf][0] + (w * 2 + i) * 1024);
      gload_lds16(Vbase + (size_t)row * S_ + kt * 64 + cs * 8,
                  (char*)&Vs[buf][0] + (w * 2 + i) * 1024);
    }
  };

  auto body = [&](int kt, int cbuf) {
    f32x16 s[2] = {};
    __builtin_amdgcn_s_setprio(1);
#pragma unroll
    for (int ds = 0; ds < 4; ds++)
#pragma unroll
      for (int kb = 0; kb < 2; kb++) {
        int row = kb * 32 + l31;
        bf16x8 kf = *(const bf16x8*)((const char*)&Ks[cbuf][0] + row * 128 +
                                     (((ds * 2 + hi) ^ (row & 7)) << 4));
        s[kb] = __builtin_amdgcn_mfma_f32_32x32x16_bf16(kf, qf[ds], s[kb], 0, 0, 0);
      }
    __builtin_amdgcn_s_setprio(0);

    if (hz) {
#pragma unroll
      for (int kb = 0; kb < 2; kb++)
#pragma unroll
        for (int i = 0; i < 16; i++) {
          int kc = kt * 64 + kb * 32 + (i & 3) + 8 * (i >> 2) + 4 * hi;
          if (mask[((size_t)b * S_ + q) * S_ + kc] == 0) s[kb][i] = -1e9f;
        }
    }

    float a0 = max3f(s[0][0], s[0][1], s[0][2]);
    float a1 = max3f(s[0][3], s[0][4], s[0][5]);
    float a2 = max3f(s[0][6], s[0][7], s[0][8]);
    float a3 = max3f(s[0][9], s[0][10], s[0][11]);
    float a4 = max3f(s[0][12], s[0][13], s[0][14]);
    float a5 = max3f(s[0][15], s[1][0], s[1][1]);
    float a6 = max3f(s[1][2], s[1][3], s[1][4]);
    float a7 = max3f(s[1][5], s[1][6], s[1][7]);
    float a8 = max3f(s[1][8], s[1][9], s[1][10]);
    float a9 = max3f(s[1][11], s[1][12], s[1][13]);
    float aa = fmaxf(s[1][14], s[1][15]);
    float b0 = max3f(a0, a1, a2);
    float b1 = max3f(a3, a4, a5);
    float b2 = max3f(a6, a7, a8);
    float b3 = max3f(a9, aa, b0);
    float mx = max3f(b1, b2, b3);
    mx = fmaxf(mx, __shfl_xor(mx, 32));

    if (!__all(mx - m <= 8.f)) {
      float mn = fmaxf(m, mx);
      float al = exp2fast(m - mn);
      m = mn;
      lsum[0] *= al;
#pragma unroll
      for (int db = 0; db < 2; db++)
#pragma unroll
        for (int i = 0; i < 16; i++) accO[db][i] *= al;
    }

#pragma unroll
    for (int kb = 0; kb < 2; kb++)
#pragma unroll
      for (int i = 0; i < 16; i++) s[kb][i] = exp2fast(s[kb][i] - m);

#pragma unroll
    for (int ks2 = 0; ks2 < 4; ks2++) {
      union { unsigned int u[4]; bf16x8 v; } pb;
      {
        const int kb = ks2 >> 1;
        const int gb = (ks2 & 1) * 8;
        unsigned int a0u = pk2(s[kb][gb + 0], s[kb][gb + 1]);
        unsigned int a1u = pk2(s[kb][gb + 2], s[kb][gb + 3]);
        unsigned int b0u = pk2(s[kb][gb + 4], s[kb][gb + 5]);
        unsigned int b1u = pk2(s[kb][gb + 6], s[kb][gb + 7]);
        unsigned int t0 = hi ? a0u : b0u;
        unsigned int t1 = hi ? a1u : b1u;
        unsigned int r0 = __shfl_xor(t0, 32);
        unsigned int r1 = __shfl_xor(t1, 32);
        pb.u[0] = hi ? r0 : a0u;
        pb.u[1] = hi ? r1 : a1u;
        pb.u[2] = hi ? b0u : r0;
        pb.u[3] = hi ? b1u : r1;
      }
      __builtin_amdgcn_s_setprio(1);
      lsum = __builtin_amdgcn_mfma_f32_32x32x16_bf16(ones.v, pb.v, lsum, 0, 0, 0);
#pragma unroll
      for (int db = 0; db < 2; db++) {
        int row = db * 32 + l31;
        bf16x8 vf = *(const bf16x8*)((const char*)&Vs[cbuf][0] + row * 128 +
                                     (((ks2 * 2 + hi) ^ (row & 7)) << 4));
        accO[db] = __builtin_amdgcn_mfma_f32_32x32x16_bf16(vf, pb.v, accO[db], 0, 0, 0);
      }
      __builtin_amdgcn_s_setprio(0);
    }
  };

  stage(0, 0);
  for (int kt2 = 0; kt2 < 32; kt2 += 2) {
    __syncthreads();
    stage(kt2 + 1, 1);
    body(kt2, 0);
    __syncthreads();
    if (kt2 + 2 < 32) stage(kt2 + 2, 0);
    body(kt2 + 1, 1);
  }

  float rl = 1.0f / lsum[0];
  const size_t orow = (((size_t)(b * S_ + q)) << 10) + h * 64;
#pragma unroll
  for (int db = 0; db < 2; db++)
#pragma unroll
    for (int rq = 0; rq < 4; rq++) {
      bf16x4v o;
#pragma unroll
      for (int j = 0; j < 4; j++) o[j] = (__bf16)(accO[db][rq * 4 + j] * rl);
      *(bf16x4v*)(Xo + orow + db * 32 + rq * 8 + hi * 4) = o;
    }
}

extern "C" void kernel_launch(void* const* d_in, const int* in_sizes, int n_in,
                              void* d_out, int out_size, void* d_ws, size_t ws_size,
                              hipStream_t stream) {
  const float* q = (const float*)d_in[0];
  const float* k = (const float*)d_in[1];
  const float* v = (const float*)d_in[2];
  const int* mask = (const int*)d_in[3];
  const float* Wq = (const float*)d_in[4];
  const float* Wk = (const float*)d_in[5];
  const float* Wv = (const float*)d_in[6];
  const float* Wo = (const float*)d_in[7];

  char* ws = (char*)d_ws;
  const size_t MB = 1024 * 1024;
  unsigned short* Xo = (unsigned short*)(ws);              // 8 MB
  unsigned short* Wq16 = (unsigned short*)(ws + 24 * MB);  // 2 MB
  unsigned short* Wk16 = (unsigned short*)(ws + 26 * MB);
  unsigned short* Wv16 = (unsigned short*)(ws + 28 * MB);
  unsigned short* Wo16 = (unsigned short*)(ws + 30 * MB);
  unsigned short* Qp = (unsigned short*)(ws + 32 * MB);    // 8 MB [B,H,S,64]
  unsigned short* Kp = (unsigned short*)(ws + 40 * MB);    // 8 MB [B,H,S,64]
  unsigned short* Vtp = (unsigned short*)(ws + 48 * MB);   // 8 MB [B,H,64,S]
  int* flag = (int*)(ws + 56 * MB);

  (void)hipMemsetAsync(flag, 0, 4, stream);
  prep<<<dim3(1024, 1, 3), 256, 0, stream>>>(mask, Wq, Wk, Wv, Wo,
                                             Wq16, Wk16, Wv16, Wo16, flag);
  gemm_qkv<<<dim3(8, 32, 3), 256, 0, stream>>>(q, k, v, Wq16, Wk16, Wv16,
                                               Qp, Kp, Vtp);
  attn<<<dim3(512), 256, 0, stream>>>(Qp, Kp, Vtp, Xo, flag, mask);
  gemm_o<<<dim3(16, 32), 256, 0, stream>>>(Xo, Wo16, (float*)d_out);
}